// Round 1
// baseline (99.775 us; speedup 1.0000x reference)
//
#include <hip/hip_runtime.h>

#define LOG2E   1.4426950408889634f
#define TWOLOG2E 2.8853900817779268f

// ---------------------------------------------------------------------------
// Kernel 1: projections  qp = queries @ Wq^T, kp = keys @ Wk^T
// grid 512 (256 q-blocks + 256 k-blocks), 128 threads, 8 rows/block
// ---------------------------------------------------------------------------
__global__ __launch_bounds__(128) void proj_kernel(
    const float* __restrict__ queries, const float* __restrict__ keys,
    const float* __restrict__ Wq, const float* __restrict__ Wk,
    float* __restrict__ qp, float* __restrict__ kp)
{
    __shared__ float xs[8][128];
    const int isK = blockIdx.x >= 256;
    const int rowBase = (blockIdx.x & 255) * 8;          // flat row in [0,2048)
    const float* __restrict__ x = isK ? keys : queries;
    const float* __restrict__ W = isK ? Wk : Wq;
    float* __restrict__ out = isK ? kp : qp;
    const int t = threadIdx.x;

    // stage 8x128 contiguous floats (rows are contiguous in flat layout)
    {
        const float4* src = (const float4*)(x + (size_t)rowBase * 128);
        float4* dst = (float4*)(&xs[0][0]);
        dst[t]       = src[t];
        dst[t + 128] = src[t + 128];
    }
    __syncthreads();

    const int h = t;                                      // output hidden idx
    float acc[8] = {0,0,0,0,0,0,0,0};
    const float4* wrow = (const float4*)(W + (size_t)h * 128);
    #pragma unroll 8
    for (int d4 = 0; d4 < 32; ++d4) {
        float4 w = wrow[d4];
        #pragma unroll
        for (int r = 0; r < 8; ++r) {
            float4 xv = *(const float4*)&xs[r][d4 * 4];   // broadcast
            acc[r] = fmaf(xv.x, w.x, acc[r]);
            acc[r] = fmaf(xv.y, w.y, acc[r]);
            acc[r] = fmaf(xv.z, w.z, acc[r]);
            acc[r] = fmaf(xv.w, w.w, acc[r]);
        }
    }
    // transpose through LDS so global writes are coalesced
    __syncthreads();
    #pragma unroll
    for (int r = 0; r < 8; ++r) xs[r][h] = acc[r];
    __syncthreads();
    {
        const float4* src = (const float4*)(&xs[0][0]);
        float4* dst = (float4*)(out + (size_t)rowBase * 128);
        dst[t]       = src[t];
        dst[t + 128] = src[t + 128];
    }
}

// ---------------------------------------------------------------------------
// Kernel 2: scores[b][q][k] = sum_h wv[h]*tanh(qp[b,q,h]+kp[b,k,h])
// grid (K/32=8, Q/32=8, B=8) = 512 blocks, 256 threads, 2q x 2k per thread
// ---------------------------------------------------------------------------
#define LDP 130   // padded LDS row stride (floats): 2-way conflicts only

__device__ __forceinline__ void tfma(float qv, float kv, float w, float& acc)
{
    float x  = qv + kv;
    float e  = __builtin_amdgcn_exp2f(x * TWOLOG2E);   // exp(2x)
    float r  = __builtin_amdgcn_rcpf(e + 1.0f);
    float th = fmaf(-2.0f, r, 1.0f);                   // tanh(x)
    acc = fmaf(w, th, acc);
}

__global__ __launch_bounds__(256) void score_kernel(
    const float* __restrict__ qp, const float* __restrict__ kp,
    const float* __restrict__ wv, float* __restrict__ scores)
{
    __shared__ float qs[32 * LDP];
    __shared__ float ks_[32 * LDP];
    __shared__ float wvs[128];

    const int kt = blockIdx.x, qt = blockIdx.y, b = blockIdx.z;
    const int t = threadIdx.x;

    const float4* qsrc = (const float4*)(qp + (size_t)(b * 256 + qt * 32) * 128);
    const float4* ksrc = (const float4*)(kp + (size_t)(b * 256 + kt * 32) * 128);
    {
        int r = t >> 3, c = (t & 7) * 16;
        #pragma unroll
        for (int j = 0; j < 4; ++j) {
            float4 v  = qsrc[t * 4 + j];
            *(float4*)&qs[r * LDP + c + j * 4] = v;
            float4 v2 = ksrc[t * 4 + j];
            *(float4*)&ks_[r * LDP + c + j * 4] = v2;
        }
        if (t < 32) *(float4*)&wvs[t * 4] = ((const float4*)wv)[t];
    }
    __syncthreads();

    const int lk = (t & 15) * 2;    // this thread's k0 (tile-local)
    const int lq = (t >> 4) * 2;    // this thread's q0 (tile-local)

    float a00 = 0.f, a01 = 0.f, a10 = 0.f, a11 = 0.f;

    #pragma unroll 4
    for (int h = 0; h < 128; h += 4) {
        float4 w4 = *(const float4*)&wvs[h];
        float4 qa = *(const float4*)&qs[lq * LDP + h];
        float4 qb = *(const float4*)&qs[(lq + 1) * LDP + h];
        float4 ka = *(const float4*)&ks_[lk * LDP + h];
        float4 kb = *(const float4*)&ks_[(lk + 1) * LDP + h];
        const float wj[4]  = {w4.x, w4.y, w4.z, w4.w};
        const float qaj[4] = {qa.x, qa.y, qa.z, qa.w};
        const float qbj[4] = {qb.x, qb.y, qb.z, qb.w};
        const float kaj[4] = {ka.x, ka.y, ka.z, ka.w};
        const float kbj[4] = {kb.x, kb.y, kb.z, kb.w};
        #pragma unroll
        for (int j = 0; j < 4; ++j) {
            tfma(qaj[j], kaj[j], wj[j], a00);
            tfma(qaj[j], kbj[j], wj[j], a01);
            tfma(qbj[j], kaj[j], wj[j], a10);
            tfma(qbj[j], kbj[j], wj[j], a11);
        }
    }

    const int q = qt * 32 + lq;
    const int k = kt * 32 + lk;
    float2 r0 = make_float2(a00, a01);
    float2 r1 = make_float2(a10, a11);
    *(float2*)&scores[((size_t)(b * 256 + q)) * 256 + k]     = r0;
    *(float2*)&scores[((size_t)(b * 256 + q + 1)) * 256 + k] = r1;
}

// ---------------------------------------------------------------------------
// Kernel 3: column stats over q axis: m[b][k] = max_q s, rZ[b][k] = 1/sum_q exp(s-m)
// grid 64 blocks (8 per batch, 32 columns each), 256 threads (32 cols x 8 q-groups)
// ---------------------------------------------------------------------------
__global__ __launch_bounds__(256) void colstat_kernel(
    const float* __restrict__ scores, float* __restrict__ m, float* __restrict__ rZ)
{
    __shared__ float red[8][33];
    const int b  = blockIdx.x >> 3;
    const int k0 = (blockIdx.x & 7) * 32;
    const int t  = threadIdx.x;
    const int kc = t & 31, qg = t >> 5;

    const float* base = scores + (size_t)b * 256 * 256 + k0 + kc;

    float mx = -3.4e38f;
    #pragma unroll 8
    for (int i = 0; i < 32; ++i)
        mx = fmaxf(mx, base[(size_t)(qg * 32 + i) * 256]);
    red[qg][kc] = mx;
    __syncthreads();
    if (qg == 0) {
        float mm = red[0][kc];
        #pragma unroll
        for (int j = 1; j < 8; ++j) mm = fmaxf(mm, red[j][kc]);
        red[0][kc] = mm;
    }
    __syncthreads();
    const float mfull = red[0][kc];
    __syncthreads();

    float s = 0.f;
    #pragma unroll 8
    for (int i = 0; i < 32; ++i)
        s += __builtin_amdgcn_exp2f((base[(size_t)(qg * 32 + i) * 256] - mfull) * LOG2E);
    red[qg][kc] = s;
    __syncthreads();
    if (qg == 0) {
        float z = 0.f;
        #pragma unroll
        for (int j = 0; j < 8; ++j) z += red[j][kc];
        m[b * 256 + k0 + kc]  = mfull;
        rZ[b * 256 + k0 + kc] = 1.0f / z;
    }
}

// ---------------------------------------------------------------------------
// Kernel 4: out[b][q][d] = sum_k exp(s[b,q,k]-m[b,k])*rZ[b,k] * v[b,k,d]
// grid B*(Q/32) = 64 blocks, 256 threads = 32 q x 8 d-groups (16 d each)
// ---------------------------------------------------------------------------
__global__ __launch_bounds__(256) void pv_kernel(
    const float* __restrict__ scores, const float* __restrict__ m,
    const float* __restrict__ rZ, const float* __restrict__ values,
    float* __restrict__ out)
{
    __shared__ float ps[32][65];
    const int b  = blockIdx.x >> 3;
    const int q0 = (blockIdx.x & 7) * 32;
    const int t  = threadIdx.x;
    const int q  = t >> 3, dg = t & 7;

    float acc[16];
    #pragma unroll
    for (int i = 0; i < 16; ++i) acc[i] = 0.f;

    const float* vbase = values + (size_t)b * 256 * 128;

    for (int kt = 0; kt < 256; kt += 64) {
        // phase A: compute p for k = kt + dg*8 .. +7 for this thread's q-row
        {
            const int k = kt + dg * 8;
            const float* srow = scores + ((size_t)(b * 256 + q0 + q)) * 256 + k;
            const float* mp = m  + b * 256 + k;
            const float* rp = rZ + b * 256 + k;
            float4 s0 = *(const float4*)(srow);
            float4 s1 = *(const float4*)(srow + 4);
            float4 m0 = *(const float4*)(mp);
            float4 m1 = *(const float4*)(mp + 4);
            float4 z0 = *(const float4*)(rp);
            float4 z1 = *(const float4*)(rp + 4);
            ps[q][dg * 8 + 0] = __builtin_amdgcn_exp2f((s0.x - m0.x) * LOG2E) * z0.x;
            ps[q][dg * 8 + 1] = __builtin_amdgcn_exp2f((s0.y - m0.y) * LOG2E) * z0.y;
            ps[q][dg * 8 + 2] = __builtin_amdgcn_exp2f((s0.z - m0.z) * LOG2E) * z0.z;
            ps[q][dg * 8 + 3] = __builtin_amdgcn_exp2f((s0.w - m0.w) * LOG2E) * z0.w;
            ps[q][dg * 8 + 4] = __builtin_amdgcn_exp2f((s1.x - m1.x) * LOG2E) * z1.x;
            ps[q][dg * 8 + 5] = __builtin_amdgcn_exp2f((s1.y - m1.y) * LOG2E) * z1.y;
            ps[q][dg * 8 + 6] = __builtin_amdgcn_exp2f((s1.z - m1.z) * LOG2E) * z1.z;
            ps[q][dg * 8 + 7] = __builtin_amdgcn_exp2f((s1.w - m1.w) * LOG2E) * z1.w;
        }
        __syncthreads();
        // phase B: accumulate over this k tile
        #pragma unroll 4
        for (int kk = 0; kk < 64; ++kk) {
            float p = ps[q][kk];
            const float4* vrow = (const float4*)(vbase + (size_t)(kt + kk) * 128 + dg * 16);
            float4 v0 = vrow[0], v1 = vrow[1], v2 = vrow[2], v3 = vrow[3];
            acc[0]  = fmaf(p, v0.x, acc[0]);
            acc[1]  = fmaf(p, v0.y, acc[1]);
            acc[2]  = fmaf(p, v0.z, acc[2]);
            acc[3]  = fmaf(p, v0.w, acc[3]);
            acc[4]  = fmaf(p, v1.x, acc[4]);
            acc[5]  = fmaf(p, v1.y, acc[5]);
            acc[6]  = fmaf(p, v1.z, acc[6]);
            acc[7]  = fmaf(p, v1.w, acc[7]);
            acc[8]  = fmaf(p, v2.x, acc[8]);
            acc[9]  = fmaf(p, v2.y, acc[9]);
            acc[10] = fmaf(p, v2.z, acc[10]);
            acc[11] = fmaf(p, v2.w, acc[11]);
            acc[12] = fmaf(p, v3.x, acc[12]);
            acc[13] = fmaf(p, v3.y, acc[13]);
            acc[14] = fmaf(p, v3.z, acc[14]);
            acc[15] = fmaf(p, v3.w, acc[15]);
        }
        __syncthreads();
    }

    float* o = out + ((size_t)(b * 256 + q0 + q)) * 128 + dg * 16;
    *(float4*)(o + 0)  = make_float4(acc[0],  acc[1],  acc[2],  acc[3]);
    *(float4*)(o + 4)  = make_float4(acc[4],  acc[5],  acc[6],  acc[7]);
    *(float4*)(o + 8)  = make_float4(acc[8],  acc[9],  acc[10], acc[11]);
    *(float4*)(o + 12) = make_float4(acc[12], acc[13], acc[14], acc[15]);
}

// ---------------------------------------------------------------------------
extern "C" void kernel_launch(void* const* d_in, const int* in_sizes, int n_in,
                              void* d_out, int out_size, void* d_ws, size_t ws_size,
                              hipStream_t stream)
{
    const float* queries = (const float*)d_in[0];  // (8,256,128)
    const float* keys    = (const float*)d_in[1];  // (8,256,128)
    const float* values  = (const float*)d_in[2];  // (8,256,128)
    const float* Wq      = (const float*)d_in[3];  // (128,128)
    const float* Wk      = (const float*)d_in[4];  // (128,128)
    const float* wv      = (const float*)d_in[5];  // (128,)
    float* out = (float*)d_out;                    // (8,256,128)

    float* ws = (float*)d_ws;
    float* qp     = ws;                    // 262144 floats
    float* kp     = ws + 262144;           // 262144 floats
    float* scores = ws + 524288;           // 524288 floats
    float* m      = ws + 1048576;          // 2048 floats
    float* rZ     = ws + 1048576 + 2048;   // 2048 floats

    proj_kernel<<<512, 128, 0, stream>>>(queries, keys, Wq, Wk, qp, kp);
    score_kernel<<<dim3(8, 8, 8), 256, 0, stream>>>(qp, kp, wv, scores);
    colstat_kernel<<<64, 256, 0, stream>>>(scores, m, rZ);
    pv_kernel<<<64, 256, 0, stream>>>(scores, m, rZ, values, out);
}

// Round 2
// 53.855 us; speedup vs baseline: 1.8527x; 1.8527x over previous
//
#include <hip/hip_runtime.h>

#define LOG2E   1.4426950408889634f
#define TWOLOG2E 2.8853900817779268f

// ---------------------------------------------------------------------------
// Kernel 1: projections  qp = queries @ Wq^T, kp = keys @ Wk^T
// grid 512 (256 q-blocks + 256 k-blocks), 128 threads, 8 rows/block
// ---------------------------------------------------------------------------
__global__ __launch_bounds__(128) void proj_kernel(
    const float* __restrict__ queries, const float* __restrict__ keys,
    const float* __restrict__ Wq, const float* __restrict__ Wk,
    float* __restrict__ qp, float* __restrict__ kp)
{
    __shared__ float xs[8][128];
    const int isK = blockIdx.x >= 256;
    const int rowBase = (blockIdx.x & 255) * 8;          // flat row in [0,2048)
    const float* __restrict__ x = isK ? keys : queries;
    const float* __restrict__ W = isK ? Wk : Wq;
    float* __restrict__ out = isK ? kp : qp;
    const int t = threadIdx.x;

    {
        const float4* src = (const float4*)(x + (size_t)rowBase * 128);
        float4* dst = (float4*)(&xs[0][0]);
        dst[t]       = src[t];
        dst[t + 128] = src[t + 128];
    }
    __syncthreads();

    const int h = t;
    float acc[8] = {0,0,0,0,0,0,0,0};
    const float4* wrow = (const float4*)(W + (size_t)h * 128);
    #pragma unroll 8
    for (int d4 = 0; d4 < 32; ++d4) {
        float4 w = wrow[d4];
        #pragma unroll
        for (int r = 0; r < 8; ++r) {
            float4 xv = *(const float4*)&xs[r][d4 * 4];
            acc[r] = fmaf(xv.x, w.x, acc[r]);
            acc[r] = fmaf(xv.y, w.y, acc[r]);
            acc[r] = fmaf(xv.z, w.z, acc[r]);
            acc[r] = fmaf(xv.w, w.w, acc[r]);
        }
    }
    __syncthreads();
    #pragma unroll
    for (int r = 0; r < 8; ++r) xs[r][h] = acc[r];
    __syncthreads();
    {
        const float4* src = (const float4*)(&xs[0][0]);
        float4* dst = (float4*)(out + (size_t)rowBase * 128);
        dst[t]       = src[t];
        dst[t + 128] = src[t + 128];
    }
}

// ---------------------------------------------------------------------------
// Kernel 2: scores[b][q][k] = sum_h wv[h]*tanh(qp[b,q,h]+kp[b,k,h])
// grid (K/32=8, Q/32=8, B=8) = 512 blocks, 256 threads, 2q x 2k per thread
// ---------------------------------------------------------------------------
#define LDP 130

__device__ __forceinline__ void tfma(float qv, float kv, float w, float& acc)
{
    float x  = qv + kv;
    float e  = __builtin_amdgcn_exp2f(x * TWOLOG2E);   // exp(2x)
    float r  = __builtin_amdgcn_rcpf(e + 1.0f);
    float th = fmaf(-2.0f, r, 1.0f);                   // tanh(x)
    acc = fmaf(w, th, acc);
}

__global__ __launch_bounds__(256) void score_kernel(
    const float* __restrict__ qp, const float* __restrict__ kp,
    const float* __restrict__ wv, float* __restrict__ scores)
{
    __shared__ float qs[32 * LDP];
    __shared__ float ks_[32 * LDP];
    __shared__ float wvs[128];

    const int kt = blockIdx.x, qt = blockIdx.y, b = blockIdx.z;
    const int t = threadIdx.x;

    const float4* qsrc = (const float4*)(qp + (size_t)(b * 256 + qt * 32) * 128);
    const float4* ksrc = (const float4*)(kp + (size_t)(b * 256 + kt * 32) * 128);
    {
        int r = t >> 3, c = (t & 7) * 16;
        #pragma unroll
        for (int j = 0; j < 4; ++j) {
            float4 v  = qsrc[t * 4 + j];
            *(float4*)&qs[r * LDP + c + j * 4] = v;
            float4 v2 = ksrc[t * 4 + j];
            *(float4*)&ks_[r * LDP + c + j * 4] = v2;
        }
        if (t < 32) *(float4*)&wvs[t * 4] = ((const float4*)wv)[t];
    }
    __syncthreads();

    const int lk = (t & 15) * 2;
    const int lq = (t >> 4) * 2;

    float a00 = 0.f, a01 = 0.f, a10 = 0.f, a11 = 0.f;

    #pragma unroll 4
    for (int h = 0; h < 128; h += 4) {
        float4 w4 = *(const float4*)&wvs[h];
        float4 qa = *(const float4*)&qs[lq * LDP + h];
        float4 qb = *(const float4*)&qs[(lq + 1) * LDP + h];
        float4 ka = *(const float4*)&ks_[lk * LDP + h];
        float4 kb = *(const float4*)&ks_[(lk + 1) * LDP + h];
        const float wj[4]  = {w4.x, w4.y, w4.z, w4.w};
        const float qaj[4] = {qa.x, qa.y, qa.z, qa.w};
        const float qbj[4] = {qb.x, qb.y, qb.z, qb.w};
        const float kaj[4] = {ka.x, ka.y, ka.z, ka.w};
        const float kbj[4] = {kb.x, kb.y, kb.z, kb.w};
        #pragma unroll
        for (int j = 0; j < 4; ++j) {
            tfma(qaj[j], kaj[j], wj[j], a00);
            tfma(qaj[j], kbj[j], wj[j], a01);
            tfma(qbj[j], kaj[j], wj[j], a10);
            tfma(qbj[j], kbj[j], wj[j], a11);
        }
    }

    const int q = qt * 32 + lq;
    const int k = kt * 32 + lk;
    *(float2*)&scores[((size_t)(b * 256 + q)) * 256 + k]     = make_float2(a00, a01);
    *(float2*)&scores[((size_t)(b * 256 + q + 1)) * 256 + k] = make_float2(a10, a11);
}

// ---------------------------------------------------------------------------
// Kernel 3: column stats over q axis: m[b][k] = max_q s, rZ[b][k] = 1/sum_q exp(s-m)
// grid 128 blocks (16 per batch, 16 columns each), 256 threads = 16 cols x 16 q-groups
// ---------------------------------------------------------------------------
__global__ __launch_bounds__(256) void colstat_kernel(
    const float* __restrict__ scores, float* __restrict__ m, float* __restrict__ rZ)
{
    __shared__ float red[16][17];
    const int b  = blockIdx.x >> 4;
    const int k0 = (blockIdx.x & 15) * 16;
    const int t  = threadIdx.x;
    const int kc = t & 15, qg = t >> 4;       // 16 cols x 16 q-groups (16 rows each)

    const float* base = scores + (size_t)b * 256 * 256 + k0 + kc;

    float mx = -3.4e38f;
    #pragma unroll 8
    for (int i = 0; i < 16; ++i)
        mx = fmaxf(mx, base[(size_t)(qg * 16 + i) * 256]);
    red[qg][kc] = mx;
    __syncthreads();
    if (qg == 0) {
        float mm = red[0][kc];
        #pragma unroll
        for (int j = 1; j < 16; ++j) mm = fmaxf(mm, red[j][kc]);
        red[0][kc] = mm;
    }
    __syncthreads();
    const float mfull = red[0][kc];
    __syncthreads();

    float s = 0.f;
    #pragma unroll 8
    for (int i = 0; i < 16; ++i)
        s += __builtin_amdgcn_exp2f((base[(size_t)(qg * 16 + i) * 256] - mfull) * LOG2E);
    red[qg][kc] = s;
    __syncthreads();
    if (qg == 0) {
        float z = 0.f;
        #pragma unroll
        for (int j = 0; j < 16; ++j) z += red[j][kc];
        m[b * 256 + k0 + kc]  = mfull;
        rZ[b * 256 + k0 + kc] = 1.0f / z;
    }
}

// ---------------------------------------------------------------------------
// Kernel 4: out[b][q][d] = sum_k exp(s[b,q,k]-m[b,k])*rZ[b,k] * v[b,k,d]
// grid B*(Q/4) = 512 blocks, 256 threads = 4 q-rows x 64 d-threads (float2 each)
// ---------------------------------------------------------------------------
__global__ __launch_bounds__(256) void pv_kernel(
    const float* __restrict__ scores, const float* __restrict__ m,
    const float* __restrict__ rZ, const float* __restrict__ values,
    float* __restrict__ out)
{
    __shared__ float ps[4][260];
    const int b  = blockIdx.x >> 6;
    const int q0 = (blockIdx.x & 63) * 4;
    const int t  = threadIdx.x;

    // phase A: p[q][k] = exp(s-m[k]) * rZ[k] for 4 q-rows x 256 k
    {
        const int q  = t >> 6;          // 0..3
        const int k  = (t & 63) * 4;    // 0..252
        float4 s0 = *(const float4*)(scores + ((size_t)(b * 256 + q0 + q)) * 256 + k);
        float4 m0 = *(const float4*)(m  + b * 256 + k);
        float4 z0 = *(const float4*)(rZ + b * 256 + k);
        float4 p;
        p.x = __builtin_amdgcn_exp2f((s0.x - m0.x) * LOG2E) * z0.x;
        p.y = __builtin_amdgcn_exp2f((s0.y - m0.y) * LOG2E) * z0.y;
        p.z = __builtin_amdgcn_exp2f((s0.z - m0.z) * LOG2E) * z0.z;
        p.w = __builtin_amdgcn_exp2f((s0.w - m0.w) * LOG2E) * z0.w;
        *(float4*)&ps[q][k] = p;
    }
    __syncthreads();

    const int q  = t >> 6;     // 0..3
    const int d2 = t & 63;     // 0..63, covers d = d2*2, d2*2+1
    const float* vcol = values + (size_t)b * 256 * 128 + d2 * 2;

    float ax = 0.f, ay = 0.f;
    #pragma unroll 8
    for (int kk = 0; kk < 256; ++kk) {
        float p = ps[q][kk];
        float2 v = *(const float2*)(vcol + (size_t)kk * 128);
        ax = fmaf(p, v.x, ax);
        ay = fmaf(p, v.y, ay);
    }

    float* o = out + ((size_t)(b * 256 + q0 + q)) * 128 + d2 * 2;
    *(float2*)o = make_float2(ax, ay);
}

// ---------------------------------------------------------------------------
extern "C" void kernel_launch(void* const* d_in, const int* in_sizes, int n_in,
                              void* d_out, int out_size, void* d_ws, size_t ws_size,
                              hipStream_t stream)
{
    const float* queries = (const float*)d_in[0];  // (8,256,128)
    const float* keys    = (const float*)d_in[1];  // (8,256,128)
    const float* values  = (const float*)d_in[2];  // (8,256,128)
    const float* Wq      = (const float*)d_in[3];  // (128,128)
    const float* Wk      = (const float*)d_in[4];  // (128,128)
    const float* wv      = (const float*)d_in[5];  // (128,)
    float* out = (float*)d_out;                    // (8,256,128)

    float* ws = (float*)d_ws;
    float* qp     = ws;                    // 262144 floats
    float* kp     = ws + 262144;           // 262144 floats
    float* scores = ws + 524288;           // 524288 floats
    float* m      = ws + 1048576;          // 2048 floats
    float* rZ     = ws + 1048576 + 2048;   // 2048 floats

    proj_kernel<<<512, 128, 0, stream>>>(queries, keys, Wq, Wk, qp, kp);
    score_kernel<<<dim3(8, 8, 8), 256, 0, stream>>>(qp, kp, wv, scores);
    colstat_kernel<<<128, 256, 0, stream>>>(scores, m, rZ);
    pv_kernel<<<512, 256, 0, stream>>>(scores, m, rZ, values, out);
}

// Round 3
// 40.685 us; speedup vs baseline: 2.4524x; 1.3237x over previous
//
#include <hip/hip_runtime.h>

#define LOG2E    1.4426950408889634f
#define TWOLOG2E 2.8853900817779268f

// ---------------------------------------------------------------------------
// Kernel 1: projections  qp = (queries @ Wq^T) * 2log2e, kp likewise.
// The scale folds exp(2x) = exp2((q'+k')) into the projection (free).
// grid 512 (256 q-blocks + 256 k-blocks), 128 threads, 8 rows/block
// ---------------------------------------------------------------------------
__global__ __launch_bounds__(128) void proj_kernel(
    const float* __restrict__ queries, const float* __restrict__ keys,
    const float* __restrict__ Wq, const float* __restrict__ Wk,
    float* __restrict__ qp, float* __restrict__ kp)
{
    __shared__ float xs[8][128];
    const int isK = blockIdx.x >= 256;
    const int rowBase = (blockIdx.x & 255) * 8;
    const float* __restrict__ x = isK ? keys : queries;
    const float* __restrict__ W = isK ? Wk : Wq;
    float* __restrict__ out = isK ? kp : qp;
    const int t = threadIdx.x;

    {
        const float4* src = (const float4*)(x + (size_t)rowBase * 128);
        float4* dst = (float4*)(&xs[0][0]);
        dst[t]       = src[t];
        dst[t + 128] = src[t + 128];
    }
    __syncthreads();

    const int h = t;
    float acc[8] = {0,0,0,0,0,0,0,0};
    const float4* wrow = (const float4*)(W + (size_t)h * 128);
    #pragma unroll 8
    for (int d4 = 0; d4 < 32; ++d4) {
        float4 w = wrow[d4];
        #pragma unroll
        for (int r = 0; r < 8; ++r) {
            float4 xv = *(const float4*)&xs[r][d4 * 4];
            acc[r] = fmaf(xv.x, w.x, acc[r]);
            acc[r] = fmaf(xv.y, w.y, acc[r]);
            acc[r] = fmaf(xv.z, w.z, acc[r]);
            acc[r] = fmaf(xv.w, w.w, acc[r]);
        }
    }
    __syncthreads();
    #pragma unroll
    for (int r = 0; r < 8; ++r) xs[r][h] = acc[r] * TWOLOG2E;
    __syncthreads();
    {
        const float4* src = (const float4*)(&xs[0][0]);
        float4* dst = (float4*)(out + (size_t)rowBase * 128);
        dst[t]       = src[t];
        dst[t + 128] = src[t + 128];
    }
}

// ---------------------------------------------------------------------------
// Kernel 2: P[b][q][k] = exp(sum_h wv[h]*tanh(q+k)) and column partial sums
// Zpart[b][qt][k] = sum_{q in tile} P.   w*tanh(x) = w + (-2w)*rcp(e^2x + 1)
// grid (K/32=8, Q/32=8, B=8) = 512 blocks, 256 threads, 2q x 2k per thread
// ---------------------------------------------------------------------------
#define LDP 130

__global__ __launch_bounds__(256) void scoreP_kernel(
    const float* __restrict__ qp, const float* __restrict__ kp,
    const float* __restrict__ wv, float* __restrict__ P,
    float* __restrict__ Zpart)
{
    __shared__ float qs[32 * LDP];
    __shared__ float ks_[32 * LDP];
    __shared__ float w2s[128];          // -2 * wv
    __shared__ float part[16][33];      // per-lqg column partials

    const int kt = blockIdx.x, qt = blockIdx.y, b = blockIdx.z;
    const int t = threadIdx.x;

    const float4* qsrc = (const float4*)(qp + (size_t)(b * 256 + qt * 32) * 128);
    const float4* ksrc = (const float4*)(kp + (size_t)(b * 256 + kt * 32) * 128);
    {
        int r = t >> 3, c = (t & 7) * 16;
        #pragma unroll
        for (int j = 0; j < 4; ++j) {
            float4 v  = qsrc[t * 4 + j];
            *(float4*)&qs[r * LDP + c + j * 4] = v;
            float4 v2 = ksrc[t * 4 + j];
            *(float4*)&ks_[r * LDP + c + j * 4] = v2;
        }
        if (t < 32) {
            float4 w = ((const float4*)wv)[t];
            *(float4*)&w2s[t * 4] = make_float4(-2.f * w.x, -2.f * w.y,
                                                -2.f * w.z, -2.f * w.w);
        }
    }
    __syncthreads();

    // wsum = sum_h wv[h] = -0.5 * sum_h w2s[h]  (broadcast LDS reads)
    float wsum = 0.f;
    #pragma unroll 8
    for (int i = 0; i < 32; ++i) {
        float4 w = *(const float4*)&w2s[i * 4];
        wsum += (w.x + w.y) + (w.z + w.w);
    }
    wsum *= -0.5f;

    const int lk = (t & 15) * 2;
    const int lq = (t >> 4) * 2;

    float a00 = 0.f, a01 = 0.f, a10 = 0.f, a11 = 0.f;

    #pragma unroll 4
    for (int h = 0; h < 128; h += 4) {
        float4 w4 = *(const float4*)&w2s[h];
        float4 qa = *(const float4*)&qs[lq * LDP + h];
        float4 qb = *(const float4*)&qs[(lq + 1) * LDP + h];
        float4 ka = *(const float4*)&ks_[lk * LDP + h];
        float4 kb = *(const float4*)&ks_[(lk + 1) * LDP + h];
        const float wj[4]  = {w4.x, w4.y, w4.z, w4.w};
        const float qaj[4] = {qa.x, qa.y, qa.z, qa.w};
        const float qbj[4] = {qb.x, qb.y, qb.z, qb.w};
        const float kaj[4] = {ka.x, ka.y, ka.z, ka.w};
        const float kbj[4] = {kb.x, kb.y, kb.z, kb.w};
        #pragma unroll
        for (int j = 0; j < 4; ++j) {
            float r00 = __builtin_amdgcn_rcpf(__builtin_amdgcn_exp2f(qaj[j] + kaj[j]) + 1.0f);
            float r01 = __builtin_amdgcn_rcpf(__builtin_amdgcn_exp2f(qaj[j] + kbj[j]) + 1.0f);
            float r10 = __builtin_amdgcn_rcpf(__builtin_amdgcn_exp2f(qbj[j] + kaj[j]) + 1.0f);
            float r11 = __builtin_amdgcn_rcpf(__builtin_amdgcn_exp2f(qbj[j] + kbj[j]) + 1.0f);
            a00 = fmaf(wj[j], r00, a00);
            a01 = fmaf(wj[j], r01, a01);
            a10 = fmaf(wj[j], r10, a10);
            a11 = fmaf(wj[j], r11, a11);
        }
    }

    // s = wsum + acc; p = exp(s) = exp2(s * log2e)
    float p00 = __builtin_amdgcn_exp2f((a00 + wsum) * LOG2E);
    float p01 = __builtin_amdgcn_exp2f((a01 + wsum) * LOG2E);
    float p10 = __builtin_amdgcn_exp2f((a10 + wsum) * LOG2E);
    float p11 = __builtin_amdgcn_exp2f((a11 + wsum) * LOG2E);

    const int q = qt * 32 + lq;
    const int k = kt * 32 + lk;
    *(float2*)&P[((size_t)(b * 256 + q)) * 256 + k]     = make_float2(p00, p01);
    *(float2*)&P[((size_t)(b * 256 + q + 1)) * 256 + k] = make_float2(p10, p11);

    // column partial sums over this tile's 32 q rows
    const int lqg = t >> 4;
    part[lqg][lk]     = p00 + p10;
    part[lqg][lk + 1] = p01 + p11;
    __syncthreads();
    if (t < 32) {
        float z = 0.f;
        #pragma unroll
        for (int g = 0; g < 16; ++g) z += part[g][t];
        Zpart[(size_t)b * 2048 + qt * 256 + kt * 32 + t] = z;
    }
}

// ---------------------------------------------------------------------------
// Kernel 3: out[b][q][d] = sum_k P[b,q,k] * c[b,k] * v[b,k,d],
//           c[b,k] = 1 / sum_qt Zpart[b][qt][k]
// grid B*(Q/4) = 512 blocks, 128 threads = 4 q-rows x 32 d-threads (float4)
// ---------------------------------------------------------------------------
__global__ __launch_bounds__(128) void pv_kernel(
    const float* __restrict__ P, const float* __restrict__ Zpart,
    const float* __restrict__ values, float* __restrict__ out)
{
    __shared__ float ps[4][260];
    const int b  = blockIdx.x >> 6;
    const int q0 = (blockIdx.x & 63) * 4;
    const int t  = threadIdx.x;

    // phase A: p[q][k] = P * c for 4 q-rows x 256 k  (8 k per thread)
    {
        const int q  = t >> 5;          // 0..3
        const int k  = (t & 31) * 8;    // 0..248
        const float* zb = Zpart + (size_t)b * 2048 + k;
        float4 z0 = make_float4(0.f, 0.f, 0.f, 0.f);
        float4 z1 = make_float4(0.f, 0.f, 0.f, 0.f);
        #pragma unroll
        for (int qt = 0; qt < 8; ++qt) {
            float4 a = *(const float4*)(zb + qt * 256);
            float4 c = *(const float4*)(zb + qt * 256 + 4);
            z0.x += a.x; z0.y += a.y; z0.z += a.z; z0.w += a.w;
            z1.x += c.x; z1.y += c.y; z1.z += c.z; z1.w += c.w;
        }
        const float* prow = P + ((size_t)(b * 256 + q0 + q)) * 256 + k;
        float4 s0 = *(const float4*)(prow);
        float4 s1 = *(const float4*)(prow + 4);
        float4 r0, r1;
        r0.x = s0.x * __builtin_amdgcn_rcpf(z0.x);
        r0.y = s0.y * __builtin_amdgcn_rcpf(z0.y);
        r0.z = s0.z * __builtin_amdgcn_rcpf(z0.z);
        r0.w = s0.w * __builtin_amdgcn_rcpf(z0.w);
        r1.x = s1.x * __builtin_amdgcn_rcpf(z1.x);
        r1.y = s1.y * __builtin_amdgcn_rcpf(z1.y);
        r1.z = s1.z * __builtin_amdgcn_rcpf(z1.z);
        r1.w = s1.w * __builtin_amdgcn_rcpf(z1.w);
        *(float4*)&ps[q][k]     = r0;
        *(float4*)&ps[q][k + 4] = r1;
    }
    __syncthreads();

    const int q  = t >> 5;     // 0..3
    const int d4 = (t & 31) * 4;
    const float* vcol = values + (size_t)b * 256 * 128 + d4;

    float ax = 0.f, ay = 0.f, az = 0.f, aw = 0.f;
    #pragma unroll 8
    for (int kk = 0; kk < 256; ++kk) {
        float p = ps[q][kk];
        float4 v = *(const float4*)(vcol + (size_t)kk * 128);
        ax = fmaf(p, v.x, ax);
        ay = fmaf(p, v.y, ay);
        az = fmaf(p, v.z, az);
        aw = fmaf(p, v.w, aw);
    }

    float* o = out + ((size_t)(b * 256 + q0 + q)) * 128 + d4;
    *(float4*)o = make_float4(ax, ay, az, aw);
}

// ---------------------------------------------------------------------------
extern "C" void kernel_launch(void* const* d_in, const int* in_sizes, int n_in,
                              void* d_out, int out_size, void* d_ws, size_t ws_size,
                              hipStream_t stream)
{
    const float* queries = (const float*)d_in[0];  // (8,256,128)
    const float* keys    = (const float*)d_in[1];  // (8,256,128)
    const float* values  = (const float*)d_in[2];  // (8,256,128)
    const float* Wq      = (const float*)d_in[3];  // (128,128)
    const float* Wk      = (const float*)d_in[4];  // (128,128)
    const float* wv      = (const float*)d_in[5];  // (128,)
    float* out = (float*)d_out;                    // (8,256,128)

    float* ws = (float*)d_ws;
    float* qp    = ws;                   // 262144 floats (scaled by 2log2e)
    float* kp    = ws + 262144;          // 262144 floats (scaled by 2log2e)
    float* P     = ws + 524288;          // 524288 floats  exp(s)
    float* Zpart = ws + 1048576;         // 8*8*256 = 16384 floats

    proj_kernel<<<512, 128, 0, stream>>>(queries, keys, Wq, Wk, qp, kp);
    scoreP_kernel<<<dim3(8, 8, 8), 256, 0, stream>>>(qp, kp, wv, P, Zpart);
    pv_kernel<<<512, 128, 0, stream>>>(P, Zpart, values, out);
}